// Round 5
// baseline (191.073 us; speedup 1.0000x reference)
//
#include <hip/hip_runtime.h>
#include <stdint.h>

#define N_PTS 256

typedef float v2f __attribute__((ext_vector_type(2)));

template<int CTRL>
__device__ __forceinline__ float dppmin_f(float x) {
    int xi = __float_as_int(x);
    int yi = __builtin_amdgcn_update_dpp(xi, xi, CTRL, 0xf, 0xf, false);
    float y = __int_as_float(yi);
    return fminf(x, y);
}

template<int CTRL>
__device__ __forceinline__ unsigned dppmin_u(unsigned x) {
    unsigned y = (unsigned)__builtin_amdgcn_update_dpp((int)x, (int)x, CTRL, 0xf, 0xf, false);
    return x < y ? x : y;  // v_min_u32
}

// One greedy round for ONE chain. Argmin is resolved entirely in the vector
// domain: per-lane key u=(slot<<6)|lane for slots achieving the wave min
// (slot-major = exact first-min-wins), then a 6-stage DPP v_min_u32 reduce.
// Only 2 VGPR->SGPR crossings per round (readlane m, readlane k) -- the
// R1-R4 versions had 6-8 (ballots + s_ff1 cascades), whose ~5-cycle
// VALU->SALU wait states dominated the 365 cyc/round cost.
__device__ __forceinline__ void round1(
    float tjx, float tjy, int lane, float& acc,
    v2f& p0, v2f& p1, v2f& p2, v2f& p3,
    unsigned vL0, unsigned vL64, unsigned vL128, unsigned vL192,
    unsigned vBAD, float vNAN)
{
    #pragma clang fp contract(off)
    v2f t; t.x = tjx; t.y = tjy;
    // packed distances (separate sub/mul/add rounding == fp32 numpy ref
    // -> identical greedy trajectory)
    v2f q0 = t - p0, q1 = t - p1, q2 = t - p2, q3 = t - p3;
    v2f s0 = q0 * q0, s1 = q1 * q1, s2 = q2 * q2, s3 = q3 * q3;
    float d0 = s0.x + s0.y;
    float d1 = s1.x + s1.y;
    float d2 = s2.x + s2.y;
    float d3 = s3.x + s3.y;

    // wave min (NaN = used candidate, ignored by v_min_f32 minNum)
    float m = fminf(fminf(fminf(d0, d1), d2), d3);
    m = dppmin_f<0x111>(m); // row_shr:1
    m = dppmin_f<0x112>(m); // row_shr:2
    m = dppmin_f<0x114>(m); // row_shr:4
    m = dppmin_f<0x118>(m); // row_shr:8
    m = dppmin_f<0x142>(m); // row_bcast:15
    m = dppmin_f<0x143>(m); // row_bcast:31
    unsigned mu = (unsigned)__builtin_amdgcn_readlane(__float_as_int(m), 63); // SGPR
    float ms = __uint_as_float(mu);

    // per-lane candidate key: lowest slot achieving the min (NaN != ms always)
    unsigned u = (d0 == ms) ? vL0
               : (d1 == ms) ? vL64
               : (d2 == ms) ? vL128
               : (d3 == ms) ? vL192
               : vBAD;
    u = dppmin_u<0x111>(u);
    u = dppmin_u<0x112>(u);
    u = dppmin_u<0x114>(u);
    u = dppmin_u<0x118>(u);
    u = dppmin_u<0x142>(u);
    u = dppmin_u<0x143>(u);
    unsigned k = (unsigned)__builtin_amdgcn_readlane((int)u, 63);  // SGPR

    // faithful to reference: se = min(m, BIG); if !(m < BIG), k = 0.
    // uint compare == float compare for non-negative finite m.
    const unsigned BIG_U = __float_as_uint(66049.0f);  // 257^2 bits
    bool ok = (mu < BIG_U);
    k = ok ? k : 0u;                       // s_cselect
    unsigned se = (mu < BIG_U) ? mu : BIG_U;
    acc += __uint_as_float(se);            // v_add_f32 with SGPR src

    // poison candidate k's x with NaN (only the owning lane+slot)
    unsigned ks = k >> 6, kl = k & 63u;
    bool hit = ((unsigned)lane == kl);
    p0.x = (hit && ks == 0) ? vNAN : p0.x;
    p1.x = (hit && ks == 1) ? vNAN : p1.x;
    p2.x = (hit && ks == 2) ? vNAN : p2.x;
    p3.x = (hit && ks == 3) ? vNAN : p3.x;
}

// 64 targets (one phase) for TWO independent batch-chains. The two round1
// bodies share nothing -> the scheduler interleaves them, filling each
// chain's DPP wait-states and SGPR-crossing hazards with the other's work
// (intra-wave ILP; R3 showed cross-wave filling does NOT happen).
__device__ __forceinline__ void phase2(
    float txX, float tyX, float txY, float tyY, int lane,
    float& accX, v2f& x0, v2f& x1, v2f& x2, v2f& x3,
    float& accY, v2f& y0, v2f& y1, v2f& y2, v2f& y3,
    unsigned vL0, unsigned vL64, unsigned vL128, unsigned vL192,
    unsigned vBAD, float vNAN)
{
    #pragma unroll 1
    for (int j = 0; j < 64; ++j) {
        float aX = __int_as_float(__builtin_amdgcn_readlane(__float_as_int(txX), j));
        float bX = __int_as_float(__builtin_amdgcn_readlane(__float_as_int(tyX), j));
        float aY = __int_as_float(__builtin_amdgcn_readlane(__float_as_int(txY), j));
        float bY = __int_as_float(__builtin_amdgcn_readlane(__float_as_int(tyY), j));
        round1(aX, bX, lane, accX, x0, x1, x2, x3, vL0, vL64, vL128, vL192, vBAD, vNAN);
        round1(aY, bY, lane, accY, y0, y1, y2, y3, vL0, vL64, vL128, vL192, vBAD, vNAN);
    }
}

// One wave handles TWO batches (ILP=2). Block = 256 threads = 4 waves = 8 batches.
__global__ __launch_bounds__(256) void greedy_match_kernel(
    const float* __restrict__ input,
    const float* __restrict__ targets,
    float* __restrict__ out,
    int B, float scale)
{
    __shared__ float wsum[4];
    const int lane = threadIdx.x & 63;
    const int wid  = threadIdx.x >> 6;
    const int bX   = blockIdx.x * 8 + wid * 2;
    const int bY   = bX + 1;
    const bool vX  = (bX < B), vY = (bY < B);
    const int cX   = vX ? bX : 0;   // clamped (dummy work if invalid)
    const int cY   = vY ? bY : 0;

    const v2f* pinX = (const v2f*)(input   + (size_t)cX * (2 * N_PTS));
    const v2f* ptgX = (const v2f*)(targets + (size_t)cX * (2 * N_PTS));
    const v2f* pinY = (const v2f*)(input   + (size_t)cY * (2 * N_PTS));
    const v2f* ptgY = (const v2f*)(targets + (size_t)cY * (2 * N_PTS));

    v2f x0 = pinX[lane], x1 = pinX[64 + lane], x2 = pinX[128 + lane], x3 = pinX[192 + lane];
    v2f tX0 = ptgX[lane], tX1 = ptgX[64 + lane], tX2 = ptgX[128 + lane], tX3 = ptgX[192 + lane];
    v2f y0 = pinY[lane], y1 = pinY[64 + lane], y2 = pinY[128 + lane], y3 = pinY[192 + lane];
    v2f tY0 = ptgY[lane], tY1 = ptgY[64 + lane], tY2 = ptgY[128 + lane], tY3 = ptgY[192 + lane];

    // loop-invariant VGPR constants (VOP3 cndmask can't take literals)
    const unsigned vL0   = (unsigned)lane;
    const unsigned vL64  = vL0 | 64u;
    const unsigned vL128 = vL0 | 128u;
    const unsigned vL192 = vL0 | 192u;
    const unsigned vBAD  = 1023u;
    const float    vNAN  = __int_as_float(0x7fc00000);

    float accX = 0.0f, accY = 0.0f;
    phase2(tX0.x, tX0.y, tY0.x, tY0.y, lane, accX, x0, x1, x2, x3,
           accY, y0, y1, y2, y3, vL0, vL64, vL128, vL192, vBAD, vNAN);
    phase2(tX1.x, tX1.y, tY1.x, tY1.y, lane, accX, x0, x1, x2, x3,
           accY, y0, y1, y2, y3, vL0, vL64, vL128, vL192, vBAD, vNAN);
    phase2(tX2.x, tX2.y, tY2.x, tY2.y, lane, accX, x0, x1, x2, x3,
           accY, y0, y1, y2, y3, vL0, vL64, vL128, vL192, vBAD, vNAN);
    phase2(tX3.x, tX3.y, tY3.x, tY3.y, lane, accX, x0, x1, x2, x3,
           accY, y0, y1, y2, y3, vL0, vL64, vL128, vL192, vBAD, vNAN);

    float a = (vX ? accX : 0.0f) + (vY ? accY : 0.0f);
    if (lane == 0) wsum[wid] = a;
    __syncthreads();
    if (threadIdx.x == 0) {
        float s = (wsum[0] + wsum[1] + wsum[2] + wsum[3]) * scale;
        atomicAdd(out, s);
    }
}

extern "C" void kernel_launch(void* const* d_in, const int* in_sizes, int n_in,
                              void* d_out, int out_size, void* d_ws, size_t ws_size,
                              hipStream_t stream) {
    const float* input   = (const float*)d_in[0];
    const float* targets = (const float*)d_in[1];
    float* out = (float*)d_out;

    const int B = in_sizes[0] / (2 * N_PTS);
    const float scale = 1.0f / ((float)B * (float)(2 * N_PTS));

    // d_out is poisoned 0xAA before every call — zero it (graph-capturable).
    hipMemsetAsync(d_out, 0, sizeof(float) * (size_t)out_size, stream);

    const int blocks = (B + 7) / 8;  // 8 batches per 256-thread block
    greedy_match_kernel<<<blocks, 256, 0, stream>>>(input, targets, out, B, scale);
}

// Round 6
// 125.625 us; speedup vs baseline: 1.5210x; 1.5210x over previous
//
#include <hip/hip_runtime.h>
#include <stdint.h>

#define N_PTS 256

typedef unsigned long long ull;
typedef float v2f __attribute__((ext_vector_type(2)));

__device__ __forceinline__ unsigned umin2(unsigned a, unsigned b) { return a < b ? a : b; }

// DPP min stage with IDENTITY old (+inf bits): invalid source lanes contribute
// +inf == no-op, exactly like the old=x form, but the identity-immediate form
// is what GCNDPPCombine can fold into a single v_min_f32_dpp (the old=x form
// compiled to v_mov + v_mov_dpp + v_min = 3 insts -> R5's measured ~145
// VALU/resolution).
template<int CTRL>
__device__ __forceinline__ float dppmin(float x) {
    int xi = __float_as_int(x);
    int yi = __builtin_amdgcn_update_dpp(0x7f800000, xi, CTRL, 0xf, 0xf, false);
    return fminf(x, __int_as_float(yi));
}

// One greedy round. Instruction-count-minimized per the R1-R5 model
// (per-SIMD time ~ total insts issued; chain length and pipe mix secondary).
__device__ __forceinline__ void round1(
    float tjx, float tjy, unsigned lane, float& acc,
    v2f& p0, v2f& p1, v2f& p2, v2f& p3, float vNAN)
{
    #pragma clang fp contract(off)
    // packed distances: v_pk_add(neg) + v_pk_mul + horizontal v_add per slot.
    // separate sub/mul/add rounding == fp32 numpy ref -> identical trajectory.
    v2f t; t.x = tjx; t.y = tjy;
    v2f q0 = t - p0, q1 = t - p1, q2 = t - p2, q3 = t - p3;
    v2f s0 = q0 * q0, s1 = q1 * q1, s2 = q2 * q2, s3 = q3 * q3;
    float d0 = s0.x + s0.y;
    float d1 = s1.x + s1.y;
    float d2 = s2.x + s2.y;
    float d3 = s3.x + s3.y;

    // wave min of live candidates (poisoned -> NaN, ignored by v_min_f32)
    float m = fminf(fminf(fminf(d0, d1), d2), d3);
    m = dppmin<0x111>(m); // row_shr:1
    m = dppmin<0x112>(m); // row_shr:2
    m = dppmin<0x114>(m); // row_shr:4
    m = dppmin<0x118>(m); // row_shr:8
    m = dppmin<0x142>(m); // row_bcast:15
    m = dppmin<0x143>(m); // row_bcast:31
    unsigned mu = (unsigned)__builtin_amdgcn_readlane(__float_as_int(m), 63); // SGPR
    float ms = __uint_as_float(mu);

    // exact first-min-wins argmin: 4 ballots (v_cmp -> SGPR pair, no cndmask),
    // then flat SALU tree. Empty ballot: ffs-1 = 0xffffffff loses the uint min.
    // NaN == ms is false -> poisoned slots never claim.
    ull e0 = __ballot(d0 == ms);
    ull e1 = __ballot(d1 == ms);
    ull e2 = __ballot(d2 == ms);
    ull e3 = __ballot(d3 == ms);
    unsigned u0 = (unsigned)(__ffsll((long long)e0) - 1);
    unsigned u1 = ((unsigned)(__ffsll((long long)e1) - 1)) | 64u;
    unsigned u2 = ((unsigned)(__ffsll((long long)e2) - 1)) | 128u;
    unsigned u3 = ((unsigned)(__ffsll((long long)e3) - 1)) | 192u;
    unsigned k  = umin2(umin2(u0, u1), umin2(u2, u3));

    // se = min(m, BIG); if !(m < BIG), k = 0. uint cmp == float cmp (m >= 0;
    // NaN bits 0x7fc00000 sort above BIG -> correct fallthrough).
    const unsigned BIG_U = __float_as_uint(66049.0f); // 257^2
    bool ok = (mu < BIG_U);
    k = ok ? k : 0u;                  // s_cselect
    unsigned se = umin2(mu, BIG_U);   // s_min_u32
    acc += __uint_as_float(se);       // v_add_f32 with SGPR src

    // poison candidate k's x with NaN (owning lane+slot only)
    unsigned ks = k >> 6, kl = k & 63u;
    bool hit = (lane == kl);          // v_cmp -> vcc
    p0.x = (hit && ks == 0) ? vNAN : p0.x;
    p1.x = (hit && ks == 1) ? vNAN : p1.x;
    p2.x = (hit && ks == 2) ? vNAN : p2.x;
    p3.x = (hit && ks == 3) ? vNAN : p3.x;
}

// 64 targets per phase (readlane needs a statically-named source register).
__device__ __forceinline__ void phase(
    float txc, float tyc, unsigned lane, float& acc,
    v2f& p0, v2f& p1, v2f& p2, v2f& p3, float vNAN)
{
    #pragma unroll 1
    for (int j = 0; j < 64; ++j) {
        float tjx = __int_as_float(__builtin_amdgcn_readlane(__float_as_int(txc), j));
        float tjy = __int_as_float(__builtin_amdgcn_readlane(__float_as_int(tyc), j));
        round1(tjx, tjy, lane, acc, p0, p1, p2, p3, vNAN);
    }
}

// One wave per batch (2048 waves = 2 waves/SIMD: R5 proved 1 wave/SIMD is
// 1.8x worse -- the second wave covers VALU occupancy + hazard bubbles).
__global__ __launch_bounds__(256) void greedy_match_kernel(
    const float* __restrict__ input,
    const float* __restrict__ targets,
    float* __restrict__ out,
    int B, float scale)
{
    __shared__ float wsum[4];
    const unsigned lane = threadIdx.x & 63;
    const int wid  = threadIdx.x >> 6;
    const int b    = blockIdx.x * 4 + wid;

    float acc = 0.0f;
    if (b < B) {
        const v2f* pin = (const v2f*)(input   + (size_t)b * (2 * N_PTS));
        const v2f* ptg = (const v2f*)(targets + (size_t)b * (2 * N_PTS));

        v2f p0 = pin[lane],       p1 = pin[64 + lane];
        v2f p2 = pin[128 + lane], p3 = pin[192 + lane];
        v2f t0 = ptg[lane],       t1 = ptg[64 + lane];
        v2f t2 = ptg[128 + lane], t3 = ptg[192 + lane];

        const float vNAN = __int_as_float(0x7fc00000);

        phase(t0.x, t0.y, lane, acc, p0, p1, p2, p3, vNAN);
        phase(t1.x, t1.y, lane, acc, p0, p1, p2, p3, vNAN);
        phase(t2.x, t2.y, lane, acc, p0, p1, p2, p3, vNAN);
        phase(t3.x, t3.y, lane, acc, p0, p1, p2, p3, vNAN);
    }

    if (lane == 0) wsum[wid] = acc;
    __syncthreads();
    if (threadIdx.x == 0) {
        float s = (wsum[0] + wsum[1] + wsum[2] + wsum[3]) * scale;
        atomicAdd(out, s);
    }
}

extern "C" void kernel_launch(void* const* d_in, const int* in_sizes, int n_in,
                              void* d_out, int out_size, void* d_ws, size_t ws_size,
                              hipStream_t stream) {
    const float* input   = (const float*)d_in[0];
    const float* targets = (const float*)d_in[1];
    float* out = (float*)d_out;

    const int B = in_sizes[0] / (2 * N_PTS);
    const float scale = 1.0f / ((float)B * (float)(2 * N_PTS));

    // d_out is poisoned 0xAA before every call — zero it (graph-capturable).
    hipMemsetAsync(d_out, 0, sizeof(float) * (size_t)out_size, stream);

    const int blocks = (B + 3) / 4;  // 4 waves (4 batches) per 256-thread block
    greedy_match_kernel<<<blocks, 256, 0, stream>>>(input, targets, out, B, scale);
}

// Round 7
// 120.766 us; speedup vs baseline: 1.5822x; 1.0402x over previous
//
#include <hip/hip_runtime.h>
#include <stdint.h>

#define N_PTS 256

typedef unsigned long long ull;
typedef float v2f __attribute__((ext_vector_type(2)));

__device__ __forceinline__ unsigned umin2(unsigned a, unsigned b) { return a < b ? a : b; }

// Single-instruction DPP max stage: old=0 + bound_ctrl=1 (invalid lanes -> 0,
// the IDENTITY of unsigned max) is the exact pattern GCNDPPCombine folds into
// one v_max_u32_dpp. R6's old=+inf/bound_ctrl=0 form stayed 3 insts/stage
// (v_mov + v_mov_dpp + v_min) -> ~100 VALU/round measured vs ~33 modeled.
template<int CTRL>
__device__ __forceinline__ unsigned dppmax(unsigned x) {
    unsigned y = (unsigned)__builtin_amdgcn_update_dpp(0, (int)x, CTRL, 0xf, 0xf, true);
    return x > y ? x : y;  // v_max_u32 (fused with the dpp mov)
}

// Wave-wide MIN of non-negative fp32 via complemented unsigned MAX:
// bit-complement reverses unsigned order exactly, so ~max(~d) == min(d)
// bitwise (ties, NaN ordering, recovered bits all identical -> the greedy
// trajectory stays bit-exact vs the numpy reference). NaN (used candidate)
// complements to 0x803fffff < any live ~d (>= 0x807fffff) -> never wins.
// Shape: row_ror 1/2/4/8 (circular within 16-lane rows, no invalid lanes)
// then row_bcast15/31 (invalid lanes read 0 = identity, harmless);
// full 64-lane max lands in lane 63.
__device__ __forceinline__ unsigned wave_cmax(float m) {
    unsigned c = ~__float_as_uint(m);
    c = dppmax<0x121>(c); // row_ror:1
    c = dppmax<0x122>(c); // row_ror:2
    c = dppmax<0x124>(c); // row_ror:4
    c = dppmax<0x128>(c); // row_ror:8
    c = dppmax<0x142>(c); // row_bcast:15
    c = dppmax<0x143>(c); // row_bcast:31
    return ~((unsigned)__builtin_amdgcn_readlane((int)c, 63)); // SGPR, = min bits
}

// One greedy round. ~34 VALU + ~22 SALU static.
__device__ __forceinline__ void round1(
    float tjx, float tjy, unsigned lane, float& acc,
    v2f& p0, v2f& p1, v2f& p2, v2f& p3, float vNAN)
{
    #pragma clang fp contract(off)
    // packed distances; separate sub/mul/add rounding == fp32 numpy ref
    v2f t; t.x = tjx; t.y = tjy;
    v2f q0 = t - p0, q1 = t - p1, q2 = t - p2, q3 = t - p3;
    v2f s0 = q0 * q0, s1 = q1 * q1, s2 = q2 * q2, s3 = q3 * q3;
    float d0 = s0.x + s0.y;
    float d1 = s1.x + s1.y;
    float d2 = s2.x + s2.y;
    float d3 = s3.x + s3.y;

    // per-lane min of 4 (NaN = used, dropped by v_min_f32 minNum), wave min
    float m = fminf(fminf(d0, d1), fminf(d2, d3));
    unsigned mu = wave_cmax(m);
    float ms = __uint_as_float(mu);

    // exact first-min-wins argmin (slot-major): 4 ballots + flat SALU tree.
    // Empty ballot: s_ff1 -> -1 = 0xffffffff, loses the uint min; -1|64 = -1.
    ull e0 = __ballot(d0 == ms);
    ull e1 = __ballot(d1 == ms);
    ull e2 = __ballot(d2 == ms);
    ull e3 = __ballot(d3 == ms);
    unsigned u0 = (unsigned)(__ffsll((long long)e0) - 1);
    unsigned u1 = ((unsigned)(__ffsll((long long)e1) - 1)) | 64u;
    unsigned u2 = ((unsigned)(__ffsll((long long)e2) - 1)) | 128u;
    unsigned u3 = ((unsigned)(__ffsll((long long)e3) - 1)) | 192u;
    unsigned k  = umin2(umin2(u0, u1), umin2(u2, u3));

    // se = min(m, BIG); if !(m < BIG), k = 0 (uint cmp == float cmp, m >= +0;
    // NaN bits sort above BIG -> falls through correctly)
    const unsigned BIG_U = __float_as_uint(66049.0f); // 257^2
    bool ok = (mu < BIG_U);
    k = ok ? k : 0u;                 // s_cselect
    unsigned se = umin2(mu, BIG_U);  // s_min_u32
    acc += __uint_as_float(se);      // v_add_f32, SGPR src

    // poison candidate k's x with NaN (owning lane+slot only)
    unsigned ks = k >> 6, kl = k & 63u;
    bool hit = (lane == kl);         // v_cmp -> vcc
    p0.x = (hit && ks == 0) ? vNAN : p0.x;
    p1.x = (hit && ks == 1) ? vNAN : p1.x;
    p2.x = (hit && ks == 2) ? vNAN : p2.x;
    p3.x = (hit && ks == 3) ? vNAN : p3.x;
}

// 64 targets per phase (readlane needs a statically-named source register).
__device__ __forceinline__ void phase(
    float txc, float tyc, unsigned lane, float& acc,
    v2f& p0, v2f& p1, v2f& p2, v2f& p3, float vNAN)
{
    #pragma unroll 1
    for (int j = 0; j < 64; ++j) {
        float tjx = __int_as_float(__builtin_amdgcn_readlane(__float_as_int(txc), j));
        float tjy = __int_as_float(__builtin_amdgcn_readlane(__float_as_int(tyc), j));
        round1(tjx, tjy, lane, acc, p0, p1, p2, p3, vNAN);
    }
}

// One wave per batch (2048 waves = 2/SIMD; R5 proved 1/SIMD is 1.8x worse).
__global__ __launch_bounds__(256) void greedy_match_kernel(
    const float* __restrict__ input,
    const float* __restrict__ targets,
    float* __restrict__ out,
    int B, float scale)
{
    __shared__ float wsum[4];
    const unsigned lane = threadIdx.x & 63;
    const int wid  = threadIdx.x >> 6;
    const int b    = blockIdx.x * 4 + wid;

    float acc = 0.0f;
    if (b < B) {
        const v2f* pin = (const v2f*)(input   + (size_t)b * (2 * N_PTS));
        const v2f* ptg = (const v2f*)(targets + (size_t)b * (2 * N_PTS));

        v2f p0 = pin[lane],       p1 = pin[64 + lane];
        v2f p2 = pin[128 + lane], p3 = pin[192 + lane];
        v2f t0 = ptg[lane],       t1 = ptg[64 + lane];
        v2f t2 = ptg[128 + lane], t3 = ptg[192 + lane];

        const float vNAN = __int_as_float(0x7fc00000);

        phase(t0.x, t0.y, lane, acc, p0, p1, p2, p3, vNAN);
        phase(t1.x, t1.y, lane, acc, p0, p1, p2, p3, vNAN);
        phase(t2.x, t2.y, lane, acc, p0, p1, p2, p3, vNAN);
        phase(t3.x, t3.y, lane, acc, p0, p1, p2, p3, vNAN);
    }

    if (lane == 0) wsum[wid] = acc;
    __syncthreads();
    if (threadIdx.x == 0) {
        float s = (wsum[0] + wsum[1] + wsum[2] + wsum[3]) * scale;
        atomicAdd(out, s);
    }
}

extern "C" void kernel_launch(void* const* d_in, const int* in_sizes, int n_in,
                              void* d_out, int out_size, void* d_ws, size_t ws_size,
                              hipStream_t stream) {
    const float* input   = (const float*)d_in[0];
    const float* targets = (const float*)d_in[1];
    float* out = (float*)d_out;

    const int B = in_sizes[0] / (2 * N_PTS);
    const float scale = 1.0f / ((float)B * (float)(2 * N_PTS));

    // d_out is poisoned 0xAA before every call — zero it (graph-capturable).
    hipMemsetAsync(d_out, 0, sizeof(float) * (size_t)out_size, stream);

    const int blocks = (B + 3) / 4;  // 4 waves (4 batches) per 256-thread block
    greedy_match_kernel<<<blocks, 256, 0, stream>>>(input, targets, out, B, scale);
}

// Round 8
// 119.828 us; speedup vs baseline: 1.5946x; 1.0078x over previous
//
#include <hip/hip_runtime.h>
#include <stdint.h>

#define N_PTS 256

typedef unsigned long long ull;
typedef float v2f __attribute__((ext_vector_type(2)));

__device__ __forceinline__ unsigned umin2(unsigned a, unsigned b) { return a < b ? a : b; }

// Single-instruction DPP max stage: old=0 + bound_ctrl=1 (invalid lanes -> 0,
// the identity of unsigned max) folds into one v_max_u32_dpp (verified by
// R7's VALUBusy drop: ~100 -> ~65 VALU/round).
template<int CTRL>
__device__ __forceinline__ unsigned dppmax(unsigned x) {
    unsigned y = (unsigned)__builtin_amdgcn_update_dpp(0, (int)x, CTRL, 0xf, 0xf, true);
    return x > y ? x : y;  // v_max_u32 (fused with the dpp mov)
}

// Wave-wide MIN of non-negative fp32 via complemented unsigned MAX (bit-exact;
// NaN complements to 0x803fffff and always loses to live distances).
__device__ __forceinline__ unsigned wave_cmax(float m) {
    unsigned c = ~__float_as_uint(m);
    c = dppmax<0x121>(c); // row_ror:1
    c = dppmax<0x122>(c); // row_ror:2
    c = dppmax<0x124>(c); // row_ror:4
    c = dppmax<0x128>(c); // row_ror:8
    c = dppmax<0x142>(c); // row_bcast:15
    c = dppmax<0x143>(c); // row_bcast:31
    return ~((unsigned)__builtin_amdgcn_readlane((int)c, 63)); // SGPR, = min bits
}

__device__ __forceinline__ void round1(
    float tjx, float tjy, unsigned lane, float& acc,
    v2f& p0, v2f& p1, v2f& p2, v2f& p3, float vNAN)
{
    #pragma clang fp contract(off)
    v2f t; t.x = tjx; t.y = tjy;
    v2f q0 = t - p0, q1 = t - p1, q2 = t - p2, q3 = t - p3;
    v2f s0 = q0 * q0, s1 = q1 * q1, s2 = q2 * q2, s3 = q3 * q3;
    float d0 = s0.x + s0.y;
    float d1 = s1.x + s1.y;
    float d2 = s2.x + s2.y;
    float d3 = s3.x + s3.y;

    float m = fminf(fminf(d0, d1), fminf(d2, d3));
    unsigned mu = wave_cmax(m);
    float ms = __uint_as_float(mu);

    // exact first-min-wins argmin (slot-major): 4 ballots + flat SALU tree.
    ull e0 = __ballot(d0 == ms);
    ull e1 = __ballot(d1 == ms);
    ull e2 = __ballot(d2 == ms);
    ull e3 = __ballot(d3 == ms);
    unsigned u0 = (unsigned)(__ffsll((long long)e0) - 1);
    unsigned u1 = ((unsigned)(__ffsll((long long)e1) - 1)) | 64u;
    unsigned u2 = ((unsigned)(__ffsll((long long)e2) - 1)) | 128u;
    unsigned u3 = ((unsigned)(__ffsll((long long)e3) - 1)) | 192u;
    unsigned k  = umin2(umin2(u0, u1), umin2(u2, u3));

    const unsigned BIG_U = __float_as_uint(66049.0f); // 257^2
    bool ok = (mu < BIG_U);
    k = ok ? k : 0u;                 // s_cselect
    unsigned se = umin2(mu, BIG_U);  // s_min_u32
    acc += __uint_as_float(se);      // v_add_f32, SGPR src

    unsigned ks = k >> 6, kl = k & 63u;
    bool hit = (lane == kl);         // v_cmp -> vcc
    p0.x = (hit && ks == 0) ? vNAN : p0.x;
    p1.x = (hit && ks == 1) ? vNAN : p1.x;
    p2.x = (hit && ks == 2) ? vNAN : p2.x;
    p3.x = (hit && ks == 3) ? vNAN : p3.x;
}

__device__ __forceinline__ void phase(
    float txc, float tyc, unsigned lane, float& acc,
    v2f& p0, v2f& p1, v2f& p2, v2f& p3, float vNAN)
{
    #pragma unroll 4
    for (int j = 0; j < 64; ++j) {
        float tjx = __int_as_float(__builtin_amdgcn_readlane(__float_as_int(txc), j));
        float tjy = __int_as_float(__builtin_amdgcn_readlane(__float_as_int(tyc), j));
        round1(tjx, tjy, lane, acc, p0, p1, p2, p3, vNAN);
    }
}

// One wave per batch, 2 waves/SIMD. The two co-resident waves run identical
// periodic code; without desync their serial cross-domain sections (DPP chain
// -> readlane -> SALU -> poison) phase-lock and can't fill each other's VALU
// gaps (the constant ~150-190 cyc/res non-VALU residual seen R1-R7).
__global__ __launch_bounds__(256) void greedy_match_kernel(
    const float* __restrict__ input,
    const float* __restrict__ targets,
    float* __restrict__ out,
    int B, float scale)
{
    __shared__ float wsum[4];
    const unsigned lane = threadIdx.x & 63;
    const int wid  = threadIdx.x >> 6;
    const int b    = blockIdx.x * 4 + wid;

    float acc = 0.0f;
    if (b < B) {
        const v2f* pin = (const v2f*)(input   + (size_t)b * (2 * N_PTS));
        const v2f* ptg = (const v2f*)(targets + (size_t)b * (2 * N_PTS));

        v2f p0 = pin[lane],       p1 = pin[64 + lane];
        v2f p2 = pin[128 + lane], p3 = pin[192 + lane];
        v2f t0 = ptg[lane],       t1 = ptg[64 + lane];
        v2f t2 = ptg[128 + lane], t3 = ptg[192 + lane];

        const float vNAN = __int_as_float(0x7fc00000);

        // ---- anti-phase desync: odd-parity blocks burn ~half a round in a
        // dependent DPP chain before entering the loop. Parity robust to both
        // linear and XCD-round-robin (stride-8) co-residency pairings.
        if ((blockIdx.x ^ (blockIdx.x >> 3)) & 1) {
            unsigned junk = __float_as_uint(p0.x) | 1u;  // every lane odd
            #pragma unroll
            for (int i = 0; i < 8; ++i) {
                junk = dppmax<0x121>(junk);  // 24 dependent cross-lane ops
                junk = dppmax<0x122>(junk);  // (max of odd values stays odd;
                junk = dppmax<0x124>(junk);  //  bound_ctrl zeros lose the max)
            }
            if ((junk & 1u) == 0u) acc += 1.0f;  // never true; defeats DCE
        }

        phase(t0.x, t0.y, lane, acc, p0, p1, p2, p3, vNAN);
        phase(t1.x, t1.y, lane, acc, p0, p1, p2, p3, vNAN);
        phase(t2.x, t2.y, lane, acc, p0, p1, p2, p3, vNAN);
        phase(t3.x, t3.y, lane, acc, p0, p1, p2, p3, vNAN);
    }

    if (lane == 0) wsum[wid] = acc;
    __syncthreads();
    if (threadIdx.x == 0) {
        float s = (wsum[0] + wsum[1] + wsum[2] + wsum[3]) * scale;
        atomicAdd(out, s);
    }
}

extern "C" void kernel_launch(void* const* d_in, const int* in_sizes, int n_in,
                              void* d_out, int out_size, void* d_ws, size_t ws_size,
                              hipStream_t stream) {
    const float* input   = (const float*)d_in[0];
    const float* targets = (const float*)d_in[1];
    float* out = (float*)d_out;

    const int B = in_sizes[0] / (2 * N_PTS);
    const float scale = 1.0f / ((float)B * (float)(2 * N_PTS));

    // d_out is poisoned 0xAA before every call — zero it (graph-capturable).
    hipMemsetAsync(d_out, 0, sizeof(float) * (size_t)out_size, stream);

    const int blocks = (B + 3) / 4;  // 4 waves (4 batches) per 256-thread block
    greedy_match_kernel<<<blocks, 256, 0, stream>>>(input, targets, out, B, scale);
}